// Round 4
// baseline (175.657 us; speedup 1.0000x reference)
//
#include <hip/hip_runtime.h>
#include <hip/hip_bf16.h>
#include <stdint.h>

// SelfAttention: B=8, C=64, N=4096, d_k=8.
// out[b,c,m] = gamma * (sum_n h[b,c,n] * softmax_n(f[:,n].g[:,m])) + x[b,c,m]
//
// K1 (fgh): MFMA projection, x read ONCE (see R3 notes). Outputs:
//   ft/gt (B,N,8) bf16 (gt pre-scaled log2e), hswz = h in attn V-B-fragment
//   order: [(b*128+nb)*4096B] + ss*1024 + hh*512 + l5*16 + ct*8 + j*2
//   = h[b][c=ct*32+l5][n=nb*32+ss*8+4*hh+j].
// K2 (attn): flash-style no-max softmax (|s|<~20, fp32 exp2 safe).
//   64 m per block, 8 waves (512 thr) split n 8x512 -> 4 waves/SIMD at
//   2 blocks/CU (grid 512). S^T C/D layout == PV A-operand layout ->
//   exp+perm-pack fully in-register. Single-copy LDS combine via ds_add_f32.

typedef short v4s __attribute__((ext_vector_type(4)));
typedef float v16f __attribute__((ext_vector_type(16)));
typedef unsigned int v4u __attribute__((ext_vector_type(4)));
typedef unsigned int v2u __attribute__((ext_vector_type(2)));

__device__ __forceinline__ unsigned bf16pair(float lo, float hi) {
    unsigned a = __builtin_bit_cast(unsigned, lo) + 0x8000u;
    unsigned b = __builtin_bit_cast(unsigned, hi) + 0x8000u;
    return (a >> 16) | (b & 0xffff0000u);
}
__device__ __forceinline__ unsigned short bf16r(float x) {
    return (unsigned short)((__builtin_bit_cast(unsigned, x) + 0x8000u) >> 16);
}
// truncating pack via v_perm: dword = [hi16(hi) | hi16(lo)]
__device__ __forceinline__ v4s pack4t(float a, float b, float c, float d) {
    v2u r;
    r.x = __builtin_amdgcn_perm(__builtin_bit_cast(unsigned, b),
                                __builtin_bit_cast(unsigned, a), 0x07060302u);
    r.y = __builtin_amdgcn_perm(__builtin_bit_cast(unsigned, d),
                                __builtin_bit_cast(unsigned, c), 0x07060302u);
    return __builtin_bit_cast(v4s, r);
}

// ---------------- K1: MFMA projection ----------------
// grid 1024 = (b<<7)|nb. Wave w<2: h rows w*32..+31; wave 2: f(0-7)+g(8-15).
__global__ __launch_bounds__(256) void fgh_kernel(
    const float* __restrict__ x, const float* __restrict__ Wq,
    const float* __restrict__ Wk, const float* __restrict__ Wv,
    unsigned int* __restrict__ ftgt,   // ft dwords [0,131072), gt [131072,262144)
    v4u* __restrict__ hswz)
{
    __shared__ v2u wfrag[1536];        // 3 row-groups x 8 kb x 64 lanes x 8B
    __shared__ v2u xfrag[512];         // 8 kb x 64 lanes x 8B
    __shared__ short hbuf[64 * 36];    // [c][nloc] pad 36 vs 32

    const int blk  = blockIdx.x;
    const int b    = blk >> 7;
    const int nb   = blk & 127;
    const int n0   = nb << 5;
    const int tid  = threadIdx.x;
    const int wave = tid >> 6;
    const int lane = tid & 63;
    const int l5   = lane & 31;
    const int hh   = lane >> 5;

    const float* xb = x + (size_t)b * 262144 + n0;

    // stage W fragments: A[row][k=kb*8+4*hf+j]
    #pragma unroll
    for (int i = 0; i < 6; ++i) {
        const int e  = tid + i * 256;
        const int w  = e >> 9;
        const int kb = (e >> 6) & 7;
        const int r  = e & 31;
        const int hf = (e >> 5) & 1;
        const int k0 = kb * 8 + hf * 4;
        float4 wv = make_float4(0.f, 0.f, 0.f, 0.f);
        if (w == 0)      wv = *(const float4*)(Wv + r * 64 + k0);
        else if (w == 1) wv = *(const float4*)(Wv + (32 + r) * 64 + k0);
        else if (r < 8)  wv = *(const float4*)(Wq + r * 64 + k0);
        else if (r < 16) {
            wv = *(const float4*)(Wk + (r - 8) * 64 + k0);
            const float s = 1.4426950408889634f;   // fold log2(e) into g
            wv.x *= s; wv.y *= s; wv.z *= s; wv.w *= s;
        }
        v2u d; d.x = bf16pair(wv.x, wv.y); d.y = bf16pair(wv.z, wv.w);
        wfrag[e] = d;
    }

    // stage x fragments: B[col=n][k=c]
    #pragma unroll
    for (int i = 0; i < 2; ++i) {
        const int e  = tid + i * 256;
        const int kb = e >> 6;
        const int nn = e & 31;
        const int hf = (e >> 5) & 1;
        const int c0 = kb * 8 + hf * 4;
        const float a0 = xb[(size_t)(c0 + 0) * 4096 + nn];
        const float a1 = xb[(size_t)(c0 + 1) * 4096 + nn];
        const float a2 = xb[(size_t)(c0 + 2) * 4096 + nn];
        const float a3 = xb[(size_t)(c0 + 3) * 4096 + nn];
        v2u d; d.x = bf16pair(a0, a1); d.y = bf16pair(a2, a3);
        xfrag[e] = d;
    }
    __syncthreads();

    if (wave < 3) {
        v16f dacc = {0.f,0.f,0.f,0.f,0.f,0.f,0.f,0.f,0.f,0.f,0.f,0.f,0.f,0.f,0.f,0.f};
        #pragma unroll
        for (int kb = 0; kb < 8; ++kb) {
            const v4s af = __builtin_bit_cast(v4s, wfrag[wave * 512 + kb * 64 + lane]);
            const v4s bf = __builtin_bit_cast(v4s, xfrag[kb * 64 + lane]);
            dacc = __builtin_amdgcn_mfma_f32_32x32x8bf16_1k(af, bf, dacc, 0, 0, 0);
        }
        // D: row=(r&3)+8*(r>>2)+4*hh, col=n0+l5
        if (wave < 2) {
            #pragma unroll
            for (int r = 0; r < 16; ++r) {
                const int rowD = (r & 3) + ((r >> 2) << 3) + (hh << 2);
                hbuf[(wave * 32 + rowD) * 36 + l5] = (short)bf16r(dacc[r]);
            }
        } else {
            const size_t nidx = (size_t)b * 4096 + n0 + l5;
            v2u f; f.x = bf16pair(dacc[0], dacc[1]); f.y = bf16pair(dacc[2], dacc[3]);
            v2u g; g.x = bf16pair(dacc[4], dacc[5]); g.y = bf16pair(dacc[6], dacc[7]);
            *(v2u*)(ftgt + nidx * 4 + hh * 2) = f;
            *(v2u*)(ftgt + 131072 + nidx * 4 + hh * 2) = g;
        }
    }
    __syncthreads();

    // assemble hswz: thread t emits 16 contiguous bytes
    const int ss  = tid >> 6;
    const int h2  = (tid >> 5) & 1;
    const int lp  = tid & 31;
    const int nl0 = ss * 8 + h2 * 4;
    const v2u lo = *(const v2u*)(hbuf + lp * 36 + nl0);          // ct=0
    const v2u hi = *(const v2u*)(hbuf + (32 + lp) * 36 + nl0);   // ct=1
    v4u o; o.x = lo.x; o.y = lo.y; o.z = hi.x; o.w = hi.y;
    hswz[(size_t)(b * 128 + nb) * 256 + tid] = o;
}

// ---------------- K2: fused attention ----------------
// grid 512 = (b<<6)|mb, m0 = mb*64. 8 waves, wave w owns n in [w*512, w*512+512).
__global__ __launch_bounds__(512, 4) void attn_kernel(
    const v4s* __restrict__ ft4,
    const v4s* __restrict__ gt4,
    const char* __restrict__ hswz,
    const float* __restrict__ x,
    const float* __restrict__ gamma,
    float* __restrict__ out)
{
    __shared__ float ldsO[64 * 65];
    __shared__ float ldsL[64];

    const int blk  = blockIdx.x;
    const int b    = blk >> 6;
    const int m0   = (blk & 63) << 6;
    const int tid  = threadIdx.x;
    const int wave = tid >> 6;
    const int lane = tid & 63;
    const int l5   = lane & 31;
    const int hh   = lane >> 5;

    // zero the combine buffers (re-poisoned 0xAA each call)
    for (int i = tid; i < 64 * 65; i += 512) ldsO[i] = 0.f;
    if (tid < 64) ldsL[tid] = 0.f;
    __syncthreads();

    // Q B-frags for both m-tiles: lane holds m, c=4*hh..+3
    const v4s qf0 = gt4[((size_t)b * 4096 + m0 + l5) * 2 + hh];
    const v4s qf1 = gt4[((size_t)b * 4096 + m0 + 32 + l5) * 2 + hh];

    v16f acc00 = {0.f,0.f,0.f,0.f,0.f,0.f,0.f,0.f,0.f,0.f,0.f,0.f,0.f,0.f,0.f,0.f};
    v16f acc01 = acc00, acc10 = acc00, acc11 = acc00;
    float lsum0 = 0.f, lsum1 = 0.f;

    const char* vb = hswz + (size_t)b * 524288 + lane * 16;
    const int nbase = wave << 9;          // 512 n per wave

    // prefetch iter 0
    v4s kf_n = ft4[((size_t)b * 4096 + nbase + l5) * 2 + hh];
    v4u vv_n[4];
    #pragma unroll
    for (int ss = 0; ss < 4; ++ss)
        vv_n[ss] = *(const v4u*)(vb + (size_t)(nbase >> 5) * 4096 + ss * 1024);

    for (int it = 0; it < 16; ++it) {
        const v4s kf = kf_n;
        v4u vv[4];
        #pragma unroll
        for (int ss = 0; ss < 4; ++ss) vv[ss] = vv_n[ss];

        const int itn = (it + 1) & 15;            // wrap: valid, unused
        const int n0n = nbase + (itn << 5);
        kf_n = ft4[((size_t)b * 4096 + n0n + l5) * 2 + hh];
        #pragma unroll
        for (int ss = 0; ss < 4; ++ss)
            vv_n[ss] = *(const v4u*)(vb + (size_t)(n0n >> 5) * 4096 + ss * 1024);

        v16f z = {0.f,0.f,0.f,0.f,0.f,0.f,0.f,0.f,0.f,0.f,0.f,0.f,0.f,0.f,0.f,0.f};
        v16f s0 = __builtin_amdgcn_mfma_f32_32x32x8bf16_1k(kf, qf0, z, 0, 0, 0);
        v16f s1 = __builtin_amdgcn_mfma_f32_32x32x8bf16_1k(kf, qf1, z, 0, 0, 0);
        // s[reg] = S^T[n=(reg&3)+8*(reg>>2)+4hh][m] in log2 domain

        #pragma unroll
        for (int ss = 0; ss < 4; ++ss) {
            float p0[4], p1[4];
            #pragma unroll
            for (int j = 0; j < 4; ++j) {
                p0[j] = __builtin_amdgcn_exp2f(s0[4 * ss + j]);
                p1[j] = __builtin_amdgcn_exp2f(s1[4 * ss + j]);
            }
            lsum0 += (p0[0] + p0[1]) + (p0[2] + p0[3]);
            lsum1 += (p1[0] + p1[1]) + (p1[2] + p1[3]);
            const v4s pf0 = pack4t(p0[0], p0[1], p0[2], p0[3]);
            const v4s pf1 = pack4t(p1[0], p1[1], p1[2], p1[3]);
            v2u lo; lo.x = vv[ss].x; lo.y = vv[ss].y;
            v2u hi; hi.x = vv[ss].z; hi.y = vv[ss].w;
            const v4s v0 = __builtin_bit_cast(v4s, lo);   // c 0-31 frag
            const v4s v1 = __builtin_bit_cast(v4s, hi);   // c 32-63 frag
            acc00 = __builtin_amdgcn_mfma_f32_32x32x8bf16_1k(pf0, v0, acc00, 0, 0, 0);
            acc01 = __builtin_amdgcn_mfma_f32_32x32x8bf16_1k(pf0, v1, acc01, 0, 0, 0);
            acc10 = __builtin_amdgcn_mfma_f32_32x32x8bf16_1k(pf1, v0, acc10, 0, 0, 0);
            acc11 = __builtin_amdgcn_mfma_f32_32x32x8bf16_1k(pf1, v1, acc11, 0, 0, 0);
        }
    }

    // fold lane/lane+32 (same m, disjoint n), then combine via LDS atomics
    lsum0 += __shfl_xor(lsum0, 32);
    lsum1 += __shfl_xor(lsum1, 32);
    if (hh == 0) {
        atomicAdd(&ldsL[l5], lsum0);
        atomicAdd(&ldsL[32 + l5], lsum1);
    }
    #pragma unroll
    for (int r = 0; r < 16; ++r) {
        const int rowD = (r & 3) + ((r >> 2) << 3) + (hh << 2);
        atomicAdd(&ldsO[rowD * 65 + l5],             acc00[r]);
        atomicAdd(&ldsO[rowD * 65 + 32 + l5],        acc01[r]);
        atomicAdd(&ldsO[(32 + rowD) * 65 + l5],      acc10[r]);
        atomicAdd(&ldsO[(32 + rowD) * 65 + 32 + l5], acc11[r]);
    }
    __syncthreads();

    // final: normalize + gamma*o + x, coalesced over m
    const float gam = gamma[0];
    const int m  = tid & 63;
    const int c0 = (tid >> 6) * 8;
    const float rL = 1.0f / ldsL[m];
    #pragma unroll
    for (int k = 0; k < 8; ++k) {
        const int c = c0 + k;
        const float O = ldsO[m * 65 + c];
        const size_t idx = ((size_t)b * 64 + c) * 4096 + m0 + m;
        out[idx] = gam * (O * rL) + x[idx];
    }
}

extern "C" void kernel_launch(void* const* d_in, const int* in_sizes, int n_in,
                              void* d_out, int out_size, void* d_ws, size_t ws_size,
                              hipStream_t stream) {
    const float* x     = (const float*)d_in[0];
    const float* Wq    = (const float*)d_in[1];
    const float* Wk    = (const float*)d_in[2];
    const float* Wv    = (const float*)d_in[3];
    const float* gamma = (const float*)d_in[4];
    float* out = (float*)d_out;

    unsigned int* ftgt = (unsigned int*)d_ws;   // ft 512KB + gt 512KB
    v4u* hswz = (v4u*)(ftgt + 262144);          // 4MB fragment-swizzled h

    hipLaunchKernelGGL(fgh_kernel, dim3(1024), dim3(256), 0, stream,
                       x, Wq, Wk, Wv, ftgt, hswz);
    hipLaunchKernelGGL(attn_kernel, dim3(512), dim3(512), 0, stream,
                       (const v4s*)ftgt, (const v4s*)(ftgt + 131072),
                       (const char*)hswz, x, gamma, out);
}

// Round 5
// 102.263 us; speedup vs baseline: 1.7177x; 1.7177x over previous
//
#include <hip/hip_runtime.h>
#include <hip/hip_bf16.h>
#include <stdint.h>

// SelfAttention: B=8, C=64, N=4096, d_k=8.
// out[b,c,m] = gamma * (sum_n h[b,c,n] * softmax_n(f[:,n].g[:,m])) + x[b,c,m]
//
// R5 key insight (from R1/R3/R4 counters): legacy v_mfma_f32_32x32x8bf16_1k
// costs ~31 cyc on gfx950 (4x the native 32x32x16 rate). attn now uses
// native mfma_f32_32x32x16_bf16:
//   QK: K padded 8->16; qf zeroed in hh=1 lanes so kf's k=8..15 garbage
//       contributes 0. S^T[n][m] C/D layout: col m=l5, row n'=(r&3)+8(r>>2)+4hh.
//   Row permutation tau (swap row-groups 4-7<->8-11, 20-23<->24-27, i.e.
//   l5^12) applied to the K-load row makes s-regs 0..7 hold n_local = 8hh+j
//   exactly = the 32x32x16 A-operand layout -> P packs sequentially, zero
//   cross-lane ops.
//   PV: 2 n-subtiles per mfma; 8 native mfma/iter replace 16 legacy.
// hswz (V) layout per 32-n tile (4096 B), B-frag order for 32x32x16:
//   offset = chunk*2048 + ct*1024 + lane*16, lane=(hh*32+l5) holding
//   h[c=ct*32+l5][n = nb*32 + chunk*16 + 8*hh + j], j=0..7.
// K1 (fgh): unchanged MFMA projection (x read once), epilogue emits new hswz.

typedef short v4s __attribute__((ext_vector_type(4)));
typedef short v8s __attribute__((ext_vector_type(8)));
typedef float v16f __attribute__((ext_vector_type(16)));
typedef unsigned int v4u __attribute__((ext_vector_type(4)));
typedef unsigned int v2u __attribute__((ext_vector_type(2)));

__device__ __forceinline__ unsigned bf16pair(float lo, float hi) {
    unsigned a = __builtin_bit_cast(unsigned, lo) + 0x8000u;
    unsigned b = __builtin_bit_cast(unsigned, hi) + 0x8000u;
    return (a >> 16) | (b & 0xffff0000u);
}
__device__ __forceinline__ unsigned short bf16r(float x) {
    return (unsigned short)((__builtin_bit_cast(unsigned, x) + 0x8000u) >> 16);
}
// truncating bf16 pack via v_perm: dword = [hi16(hi) | hi16(lo)]
__device__ __forceinline__ unsigned packt(float lo, float hi) {
    return __builtin_amdgcn_perm(__builtin_bit_cast(unsigned, hi),
                                 __builtin_bit_cast(unsigned, lo), 0x07060302u);
}

// ---------------- K1: MFMA projection ----------------
// grid 1024 = (b<<7)|nb. Wave w<2: h rows w*32..+31; wave 2: f(0-7)+g(8-15).
__global__ __launch_bounds__(256) void fgh_kernel(
    const float* __restrict__ x, const float* __restrict__ Wq,
    const float* __restrict__ Wk, const float* __restrict__ Wv,
    unsigned int* __restrict__ ftgt,   // ft dwords [0,131072), gt [131072,262144)
    v4u* __restrict__ hswz)
{
    __shared__ v2u wfrag[1536];        // 3 row-groups x 8 kb x 64 lanes x 8B
    __shared__ v2u xfrag[512];         // 8 kb x 64 lanes x 8B
    __shared__ short hbuf[64 * 36];    // [c][nloc] pad 36 (72B rows, 8B-aligned)

    const int blk  = blockIdx.x;
    const int b    = blk >> 7;
    const int nb   = blk & 127;
    const int n0   = nb << 5;
    const int tid  = threadIdx.x;
    const int wave = tid >> 6;
    const int lane = tid & 63;
    const int l5   = lane & 31;
    const int hh   = lane >> 5;

    const float* xb = x + (size_t)b * 262144 + n0;

    // stage W fragments: A[row][k=kb*8+4*hf+j]  (legacy 32x32x8 frags; mfma
    // count here is negligible so legacy shape is fine)
    #pragma unroll
    for (int i = 0; i < 6; ++i) {
        const int e  = tid + i * 256;
        const int w  = e >> 9;
        const int kb = (e >> 6) & 7;
        const int r  = e & 31;
        const int hf = (e >> 5) & 1;
        const int k0 = kb * 8 + hf * 4;
        float4 wv = make_float4(0.f, 0.f, 0.f, 0.f);
        if (w == 0)      wv = *(const float4*)(Wv + r * 64 + k0);
        else if (w == 1) wv = *(const float4*)(Wv + (32 + r) * 64 + k0);
        else if (r < 8)  wv = *(const float4*)(Wq + r * 64 + k0);
        else if (r < 16) {
            wv = *(const float4*)(Wk + (r - 8) * 64 + k0);
            const float s = 1.4426950408889634f;   // fold log2(e) into g
            wv.x *= s; wv.y *= s; wv.z *= s; wv.w *= s;
        }
        v2u d; d.x = bf16pair(wv.x, wv.y); d.y = bf16pair(wv.z, wv.w);
        wfrag[e] = d;
    }

    // stage x fragments: B[col=n][k=c]
    #pragma unroll
    for (int i = 0; i < 2; ++i) {
        const int e  = tid + i * 256;
        const int kb = e >> 6;
        const int nn = e & 31;
        const int hf = (e >> 5) & 1;
        const int c0 = kb * 8 + hf * 4;
        const float a0 = xb[(size_t)(c0 + 0) * 4096 + nn];
        const float a1 = xb[(size_t)(c0 + 1) * 4096 + nn];
        const float a2 = xb[(size_t)(c0 + 2) * 4096 + nn];
        const float a3 = xb[(size_t)(c0 + 3) * 4096 + nn];
        v2u d; d.x = bf16pair(a0, a1); d.y = bf16pair(a2, a3);
        xfrag[e] = d;
    }
    __syncthreads();

    if (wave < 3) {
        v16f dacc = {0.f,0.f,0.f,0.f,0.f,0.f,0.f,0.f,0.f,0.f,0.f,0.f,0.f,0.f,0.f,0.f};
        #pragma unroll
        for (int kb = 0; kb < 8; ++kb) {
            const v4s af = __builtin_bit_cast(v4s, wfrag[wave * 512 + kb * 64 + lane]);
            const v4s bf = __builtin_bit_cast(v4s, xfrag[kb * 64 + lane]);
            dacc = __builtin_amdgcn_mfma_f32_32x32x8bf16_1k(af, bf, dacc, 0, 0, 0);
        }
        // D: row=(r&3)+8*(r>>2)+4*hh, col=n0+l5
        if (wave < 2) {
            #pragma unroll
            for (int r = 0; r < 16; ++r) {
                const int rowD = (r & 3) + ((r >> 2) << 3) + (hh << 2);
                hbuf[(wave * 32 + rowD) * 36 + l5] = (short)bf16r(dacc[r]);
            }
        } else {
            const size_t nidx = (size_t)b * 4096 + n0 + l5;
            v2u f; f.x = bf16pair(dacc[0], dacc[1]); f.y = bf16pair(dacc[2], dacc[3]);
            v2u g; g.x = bf16pair(dacc[4], dacc[5]); g.y = bf16pair(dacc[6], dacc[7]);
            *(v2u*)(ftgt + nidx * 4 + hh * 2) = f;
            *(v2u*)(ftgt + 131072 + nidx * 4 + hh * 2) = g;
        }
    }
    __syncthreads();

    // assemble hswz for 32x32x16 B-frag: thread t emits 16 contiguous bytes:
    // t = chunk*128 + ct*64 + hh2*32 + lp -> h[c=ct*32+lp][n=chunk*16+hh2*8+j]
    const int chunk = tid >> 7;
    const int ct    = (tid >> 6) & 1;
    const int hh2   = (tid >> 5) & 1;
    const int lp    = tid & 31;
    const short* src = hbuf + (ct * 32 + lp) * 36 + chunk * 16 + hh2 * 8;
    const v2u lo = *(const v2u*)(src);
    const v2u hi = *(const v2u*)(src + 4);
    v4u o; o.x = lo.x; o.y = lo.y; o.z = hi.x; o.w = hi.y;
    hswz[(size_t)(b * 128 + nb) * 256 + tid] = o;
}

// ---------------- K2: fused attention (native 32x32x16 MFMA) ----------------
// grid 512 = (b<<6)|mb, m0 = mb*64. 4 waves, wave w owns n in [w*1024, +1024).
__global__ __launch_bounds__(256, 2) void attn_kernel(
    const v4u* __restrict__ ft16,     // [b][n] 16B rows (8 bf16)
    const v4u* __restrict__ gt16,
    const char* __restrict__ hswz,
    const float* __restrict__ x,
    const float* __restrict__ gamma,
    float* __restrict__ out)
{
    __shared__ float ldsO[2][64 * 65];
    __shared__ float ldsL[2][64];

    const int blk  = blockIdx.x;
    const int b    = blk >> 6;
    const int m0   = (blk & 63) << 6;
    const int tid  = threadIdx.x;
    const int wave = tid >> 6;
    const int lane = tid & 63;
    const int l5   = lane & 31;
    const int hh   = lane >> 5;

    // tau: swap row-groups 4-7<->8-11 and 20-23<->24-27 (loop-invariant)
    int krow = l5;
    if (((l5 >> 2) ^ (l5 >> 3)) & 1) krow = l5 ^ 12;

    // Q B-frags: col m, k=8*hh+j. hh=1 half is the K-padding -> zero.
    v8s qf0 = __builtin_bit_cast(v8s, gt16[(size_t)b * 4096 + m0 + l5]);
    v8s qf1 = __builtin_bit_cast(v8s, gt16[(size_t)b * 4096 + m0 + 32 + l5]);
    if (hh) { qf0 = (v8s)0; qf1 = (v8s)0; }

    v16f acc00 = {0.f,0.f,0.f,0.f,0.f,0.f,0.f,0.f,0.f,0.f,0.f,0.f,0.f,0.f,0.f,0.f};
    v16f acc01 = acc00, acc10 = acc00, acc11 = acc00;
    float lsum0 = 0.f, lsum1 = 0.f;

    const char* vb = hswz + (size_t)b * 524288 + lane * 16;
    const int nbase = wave << 10;

    // prefetch iter 0
    v4u kf_n = ft16[(size_t)b * 4096 + nbase + krow];
    v4u vv_n[4];
    #pragma unroll
    for (int q = 0; q < 4; ++q)
        vv_n[q] = *(const v4u*)(vb + (size_t)(nbase >> 5) * 4096 + q * 1024);

    for (int it = 0; it < 32; ++it) {
        const v8s kf = __builtin_bit_cast(v8s, kf_n);
        v4u vv[4];
        #pragma unroll
        for (int q = 0; q < 4; ++q) vv[q] = vv_n[q];

        const int itn = (it + 1) & 31;            // wrap: valid, unused
        const int n0n = nbase + (itn << 5);
        kf_n = ft16[(size_t)b * 4096 + n0n + krow];
        #pragma unroll
        for (int q = 0; q < 4; ++q)
            vv_n[q] = *(const v4u*)(vb + (size_t)(n0n >> 5) * 4096 + q * 1024);

        v16f z = {0.f,0.f,0.f,0.f,0.f,0.f,0.f,0.f,0.f,0.f,0.f,0.f,0.f,0.f,0.f,0.f};
        v16f s0 = __builtin_amdgcn_mfma_f32_32x32x16_bf16(kf, qf0, z, 0, 0, 0);
        v16f s1 = __builtin_amdgcn_mfma_f32_32x32x16_bf16(kf, qf1, z, 0, 0, 0);
        // after tau: s[reg 0..7] = P(n_local = 8hh + reg), regs 8..15 likewise
        // for n_local 16..31  -> sequential pack = 32x32x16 A-operand layout.

        float p0[16], p1[16];
        #pragma unroll
        for (int j = 0; j < 16; ++j) {
            p0[j] = __builtin_amdgcn_exp2f(s0[j]);
            p1[j] = __builtin_amdgcn_exp2f(s1[j]);
        }
        #pragma unroll
        for (int j = 0; j < 16; ++j) { lsum0 += p0[j]; lsum1 += p1[j]; }

        v4u a0c0, a0c1, a1c0, a1c1;
        a0c0.x = packt(p0[0], p0[1]);  a0c0.y = packt(p0[2], p0[3]);
        a0c0.z = packt(p0[4], p0[5]);  a0c0.w = packt(p0[6], p0[7]);
        a0c1.x = packt(p0[8], p0[9]);  a0c1.y = packt(p0[10], p0[11]);
        a0c1.z = packt(p0[12], p0[13]); a0c1.w = packt(p0[14], p0[15]);
        a1c0.x = packt(p1[0], p1[1]);  a1c0.y = packt(p1[2], p1[3]);
        a1c0.z = packt(p1[4], p1[5]);  a1c0.w = packt(p1[6], p1[7]);
        a1c1.x = packt(p1[8], p1[9]);  a1c1.y = packt(p1[10], p1[11]);
        a1c1.z = packt(p1[12], p1[13]); a1c1.w = packt(p1[14], p1[15]);

        const v8s pA0 = __builtin_bit_cast(v8s, a0c0);  // m-tile0, n 0-15
        const v8s pA1 = __builtin_bit_cast(v8s, a0c1);  // m-tile0, n 16-31
        const v8s pB0 = __builtin_bit_cast(v8s, a1c0);  // m-tile1, n 0-15
        const v8s pB1 = __builtin_bit_cast(v8s, a1c1);  // m-tile1, n 16-31
        const v8s V00 = __builtin_bit_cast(v8s, vv[0]); // n 0-15,  c 0-31
        const v8s V01 = __builtin_bit_cast(v8s, vv[1]); // n 0-15,  c 32-63
        const v8s V10 = __builtin_bit_cast(v8s, vv[2]); // n 16-31, c 0-31
        const v8s V11 = __builtin_bit_cast(v8s, vv[3]); // n 16-31, c 32-63

        acc00 = __builtin_amdgcn_mfma_f32_32x32x16_bf16(pA0, V00, acc00, 0, 0, 0);
        acc01 = __builtin_amdgcn_mfma_f32_32x32x16_bf16(pA0, V01, acc01, 0, 0, 0);
        acc10 = __builtin_amdgcn_mfma_f32_32x32x16_bf16(pB0, V00, acc10, 0, 0, 0);
        acc11 = __builtin_amdgcn_mfma_f32_32x32x16_bf16(pB0, V01, acc11, 0, 0, 0);
        acc00 = __builtin_amdgcn_mfma_f32_32x32x16_bf16(pA1, V10, acc00, 0, 0, 0);
        acc01 = __builtin_amdgcn_mfma_f32_32x32x16_bf16(pA1, V11, acc01, 0, 0, 0);
        acc10 = __builtin_amdgcn_mfma_f32_32x32x16_bf16(pB1, V10, acc10, 0, 0, 0);
        acc11 = __builtin_amdgcn_mfma_f32_32x32x16_bf16(pB1, V11, acc11, 0, 0, 0);
    }

    // fold lane/lane+32 (same m, disjoint n)
    lsum0 += __shfl_xor(lsum0, 32);
    lsum1 += __shfl_xor(lsum1, 32);

    // 2-copy phase-add combine (R3-proven; no LDS atomics)
    if (wave < 2) {
        float* P = &ldsO[wave][0];
        #pragma unroll
        for (int r = 0; r < 16; ++r) {
            const int rowD = (r & 3) + ((r >> 2) << 3) + (hh << 2);
            P[rowD * 65 + l5]             = acc00[r];
            P[rowD * 65 + 32 + l5]        = acc01[r];
            P[(32 + rowD) * 65 + l5]      = acc10[r];
            P[(32 + rowD) * 65 + 32 + l5] = acc11[r];
        }
        if (hh == 0) { ldsL[wave][l5] = lsum0; ldsL[wave][32 + l5] = lsum1; }
    }
    __syncthreads();
    if (wave >= 2) {
        float* P = &ldsO[wave - 2][0];
        #pragma unroll
        for (int r = 0; r < 16; ++r) {
            const int rowD = (r & 3) + ((r >> 2) << 3) + (hh << 2);
            P[rowD * 65 + l5]             += acc00[r];
            P[rowD * 65 + 32 + l5]        += acc01[r];
            P[(32 + rowD) * 65 + l5]      += acc10[r];
            P[(32 + rowD) * 65 + 32 + l5] += acc11[r];
        }
        if (hh == 0) { ldsL[wave - 2][l5] += lsum0; ldsL[wave - 2][32 + l5] += lsum1; }
    }
    __syncthreads();

    // final: normalize + gamma*o + x, coalesced over m
    const float gam = gamma[0];
    const int m  = tid & 63;
    const int c0 = (tid >> 6) * 16;
    const float L = ldsL[0][m] + ldsL[1][m];
    const float rL = 1.0f / L;
    #pragma unroll
    for (int k = 0; k < 16; ++k) {
        const int c = c0 + k;
        const float O = ldsO[0][m * 65 + c] + ldsO[1][m * 65 + c];
        const size_t idx = ((size_t)b * 64 + c) * 4096 + m0 + m;
        out[idx] = gam * (O * rL) + x[idx];
    }
}

extern "C" void kernel_launch(void* const* d_in, const int* in_sizes, int n_in,
                              void* d_out, int out_size, void* d_ws, size_t ws_size,
                              hipStream_t stream) {
    const float* x     = (const float*)d_in[0];
    const float* Wq    = (const float*)d_in[1];
    const float* Wk    = (const float*)d_in[2];
    const float* Wv    = (const float*)d_in[3];
    const float* gamma = (const float*)d_in[4];
    float* out = (float*)d_out;

    unsigned int* ftgt = (unsigned int*)d_ws;   // ft 512KB + gt 512KB
    v4u* hswz = (v4u*)(ftgt + 262144);          // 4MB fragment-swizzled h

    hipLaunchKernelGGL(fgh_kernel, dim3(1024), dim3(256), 0, stream,
                       x, Wq, Wk, Wv, ftgt, hswz);
    hipLaunchKernelGGL(attn_kernel, dim3(512), dim3(256), 0, stream,
                       (const v4u*)ftgt, (const v4u*)(ftgt + 131072),
                       (const char*)hswz, x, gamma, out);
}